// Round 8
// baseline (67.556 us; speedup 1.0000x reference)
//
#include <hip/hip_runtime.h>

#define TOT 288
#define W1C 6.2340979026f   // 2*pi*127/128

typedef short short8 __attribute__((ext_vector_type(8)));
typedef float f32x4 __attribute__((ext_vector_type(4)));
typedef unsigned short u16;
typedef u16 u16x8 __attribute__((ext_vector_type(8)));

__device__ __forceinline__ u16 f2bf(float f) {
    unsigned u = __builtin_bit_cast(unsigned, f);
    u += 0x7fffu + ((u >> 16) & 1u);
    return (u16)(u >> 16);
}
__device__ __forceinline__ float2 cmul(float2 a, float2 b) {
    return make_float2(a.x * b.x - a.y * b.y, a.x * b.y + a.y * b.x);
}
__device__ __forceinline__ float2 cfma(float2 a, float2 b, float2 c) {
    return make_float2(c.x + a.x * b.x - a.y * b.y, c.y + a.x * b.y + a.y * b.x);
}
__device__ __forceinline__ void chi_basis(int f, float2 c[3]) {
    if (f == 0) {
        c[0] = make_float2(1.f, 0.f); c[1] = make_float2(0.f, 0.f); c[2] = make_float2(0.f, 0.f);
    } else {
        float w = W1C * (float)f;
        float iw = 1.0f / w;
        c[0] = make_float2(0.f, 0.f);
        c[1] = make_float2(0.f, -iw);
        c[2] = make_float2(-iw * iw, 0.f);
    }
}

// ---------------- workspace layout (float offsets) ----------------
// alpha  :      256  (131072)   [b][i][f][g] float2
// T1     :   131328  (1048576)  [bi][f=16][x=128] float2 (column-DFT intermediate)
// Dv     :  1179904  (18432)    [o][i][jk=9] float2
// or1    :  1704192  (131072)   [b][o][f][g] float2
// S      :  1966336  (262144)   [o][nm=16][pq=256] float2
// fA     :  6160640  (2048)     bf16 Fourier A table
// fB     :  6162688  (2048)     bf16 Fourier B table
// or2p   :  6164736  (1048576)  partial or2 [ic=8][bo=256][pq=256] float2

// ============ k_pre: A1 col-DFT (0..2047) | S (2048..2079) | D (2080..2207) | tf (2208)
__global__ __launch_bounds__(256) void k_pre(const float* __restrict__ x,
                                             const float* __restrict__ wr,
                                             const float* __restrict__ wi,
                                             float2* __restrict__ T1,
                                             float2* __restrict__ Sv,
                                             float2* __restrict__ Dv,
                                             u16* __restrict__ fA, u16* __restrict__ fB) {
    const int bid = blockIdx.x;
    const int t = threadIdx.x;

    if (bid < 2048) {
        // ----- A1: T1[bi,f,x] = sum_y X[bi,y,x] e^{-2pi i f y/128} -----
        // block = (bi, fp); thread: x = t&127, f = fp*2 + (t>>7). 8 blocks/CU.
        int bi = bid >> 3;
        int f = (bid & 7) * 2 + (t >> 7);
        int xc = t & 127;
        const float* xp = x + (size_t)bi * 16384 + xc;
        float sr, ss;
        sincosf(0.049087385212340517f * (float)f, &ss, &sr);   // step = (sr, -ss)
        float cr = 1.f, ci = 0.f;
        float ar = 0.f, ai = 0.f;
#pragma unroll 4
        for (int y = 0; y < 128; ++y) {
            float xv = xp[y * 128];
            ar += cr * xv;
            ai += ci * xv;
            float nr = cr * sr + ci * ss;
            ci = ci * sr - cr * ss;
            cr = nr;
        }
        T1[(size_t)(bi * 16 + f) * 128 + xc] = make_float2(ar, ai);
    } else if (bid < 2080) {
        // ----- S_o[n,m,p,q] Taylor moments for x2 polynomial -----
        int o = bid - 2048;
        int p = t >> 4, q = t & 15;
        float Sr[4][4], Si[4][4];
#pragma unroll
        for (int n = 0; n < 4; ++n)
#pragma unroll
            for (int m = 0; m < 4; ++m) { Sr[n][m] = 0.f; Si[n][m] = 0.f; }
        for (int i = 0; i < 32; ++i) {
            int io = i * 32 + o;
            float p1r = wr[io * TOT + p],      p1i = wi[io * TOT + p];
            float p2r = wr[io * TOT + 16 + q], p2i = wi[io * TOT + 16 + q];
            float a1r[4], a1i[4], a2r[4], a2i[4];
            a1r[0] = 1.f; a1i[0] = 0.f;
            a2r[0] = 1.f; a2i[0] = 0.f;
#pragma unroll
            for (int n = 1; n < 4; ++n) {
                a1r[n] = a1r[n-1] * p1r - a1i[n-1] * p1i;
                a1i[n] = a1r[n-1] * p1i + a1i[n-1] * p1r;
                a2r[n] = a2r[n-1] * p2r - a2i[n-1] * p2i;
                a2i[n] = a2r[n-1] * p2i + a2i[n-1] * p2r;
            }
#pragma unroll
            for (int n = 0; n < 4; ++n)
#pragma unroll
                for (int m = 0; m < 4; ++m) {
                    Sr[n][m] += a1r[n] * a2r[m] - a1i[n] * a2i[m];
                    Si[n][m] += a1r[n] * a2i[m] + a1i[n] * a2r[m];
                }
        }
        const float facs[4] = {1.f, 1.f, 0.5f, 0.16666666666f};
        const float isz = 1.0f / 16384.0f;
#pragma unroll
        for (int n = 0; n < 4; ++n)
#pragma unroll
            for (int m = 0; m < 4; ++m) {
                float fac = facs[n] * facs[m] * isz;
                Sv[(size_t)(o * 16 + n * 4 + m) * 256 + t] =
                    make_float2(Sr[n][m] * fac, Si[n][m] * fac);
            }
    } else if (bid < 2208) {
        // ----- D_jk[i,o] = sum_pq phi_j[p] * R[p,q] * psi_k[q] -----
        int base = (bid - 2080) * 8;
        int wp = t >> 6, l = t & 63;
#pragma unroll
        for (int s = 0; s < 2; ++s) {
            int io = base + wp * 2 + s;
            float2 Dacc[9];
#pragma unroll
            for (int jk = 0; jk < 9; ++jk) Dacc[jk] = make_float2(0.f, 0.f);
#pragma unroll
            for (int k = 0; k < 4; ++k) {
                int e = l + 64 * k;
                int p = e >> 4, q = e & 15;
                float2 p1 = make_float2(wr[io * TOT + p], wi[io * TOT + p]);
                float i1 = 1.0f / (p1.x * p1.x + p1.y * p1.y);
                float2 phip = make_float2(-p1.x * i1, p1.y * i1);
                float2 p2 = make_float2(wr[io * TOT + 16 + q], wi[io * TOT + 16 + q]);
                float i2 = 1.0f / (p2.x * p2.x + p2.y * p2.y);
                float2 psip = make_float2(-p2.x * i2, p2.y * i2);
                float2 R = make_float2(wr[io * TOT + 32 + e], wi[io * TOT + 32 + e]);
                float2 Rphi[3] = {cmul(R, phip), R, cmul(R, p1)};
                float2 psi[3] = {psip, make_float2(1.f, 0.f), p2};
#pragma unroll
                for (int j = 0; j < 3; ++j)
#pragma unroll
                    for (int k2 = 0; k2 < 3; ++k2)
                        Dacc[j * 3 + k2] = cfma(Rphi[j], psi[k2], Dacc[j * 3 + k2]);
            }
#pragma unroll
            for (int jk = 0; jk < 9; ++jk) {
#pragma unroll
                for (int m = 32; m >= 1; m >>= 1) {
                    Dacc[jk].x += __shfl_xor(Dacc[jk].x, m);
                    Dacc[jk].y += __shfl_xor(Dacc[jk].y, m);
                }
            }
            if (l == 0) {
                int o = io & 31, i = io >> 5;
#pragma unroll
                for (int jk = 0; jk < 9; ++jk)
                    Dv[(size_t)(o * 32 + i) * 9 + jk] = Dacc[jk];
            }
        }
    } else {
        // ----- tf: Fourier bf16 tables -----
        for (int cidx = t; cidx < 1024; cidx += 256) {
            int tbl = cidx >> 9, mc = cidx & 511;
            int z = mc >> 2, cp = mc & 3;
            int c = cp ^ ((z >> 1) & 3);
            u16x8 v;
#pragma unroll
            for (int j = 0; j < 8; ++j) {
                int k = c * 8 + j, f = k & 15, part = k >> 4;
                float th = 0.049087385212340517f * (float)((f * z) & 127);
                float s, cs;
                sincosf(th, &s, &cs);
                float val = part ? ((tbl == 0) ? s : -s) : cs;
                v[j] = f2bf(val);
            }
            u16* dst = (tbl == 0 ? fA : fB) + mc * 8;
            *(u16x8*)dst = v;
        }
    }
}

// ============ k_alpha2: row DFT. alpha[bi,f,g] = sum_x T1[bi,f,x] e^{-2pi i g x/128}
// 256 blocks (1/CU); 2 independent rotation chains (x, x+64) for ILP.
__global__ __launch_bounds__(256) void k_alpha2(const float2* __restrict__ T1,
                                                float2* __restrict__ alpha) {
    const int bi = blockIdx.x;
    const int t = threadIdx.x;
    const int f = t >> 4, g = t & 15;
    const float2* tp = T1 + (size_t)(bi * 16 + f) * 128;

    float sr, ss;
    sincosf(0.049087385212340517f * (float)g, &ss, &sr);  // step = (sr, -ss)
    float c0r = 1.f, c0i = 0.f;
    float c1r = (g & 1) ? -1.f : 1.f, c1i = 0.f;          // e^{-i pi g}
    float a0r = 0.f, a0i = 0.f, a1r = 0.f, a1i = 0.f;
#pragma unroll 4
    for (int xx = 0; xx < 64; ++xx) {
        float2 v0 = tp[xx];
        float2 v1 = tp[xx + 64];
        a0r += v0.x * c0r - v0.y * c0i;
        a0i += v0.x * c0i + v0.y * c0r;
        a1r += v1.x * c1r - v1.y * c1i;
        a1i += v1.x * c1i + v1.y * c1r;
        float n0 = c0r * sr + c0i * ss;
        c0i = c0i * sr - c0r * ss;
        c0r = n0;
        float n1 = c1r * sr + c1i * ss;
        c1i = c1i * sr - c1r * ss;
        c1r = n1;
    }
    alpha[bi * 256 + t] = make_float2(a0r + a1r, a0i + a1i);
}

// ============ k_mid: or1 (0..255) | or2p (256..2303)
__global__ __launch_bounds__(256) void k_mid(const float* __restrict__ wr,
                                             const float* __restrict__ wi,
                                             const float2* __restrict__ alpha,
                                             const float2* __restrict__ Dv,
                                             float2* __restrict__ or1,
                                             float2* __restrict__ or2p) {
    __shared__ float2 CaL[4][9];
    const int bid = blockIdx.x;
    const int t = threadIdx.x;

    if (bid < 256) {
        int bo = bid;
        int b = bo >> 5, o = bo & 31;
        int f = t >> 4, g = t & 15;
        float2 X[3], Xi[3];
        chi_basis(f, X);
        chi_basis(g, Xi);
        float2 B[9];
#pragma unroll
        for (int j = 0; j < 3; ++j)
#pragma unroll
            for (int k = 0; k < 3; ++k)
                B[j * 3 + k] = cmul(X[j], Xi[k]);
        float2 acc = make_float2(0.f, 0.f);
        for (int i = 0; i < 32; ++i) {
            const float2* Dp = Dv + (size_t)(o * 32 + i) * 9;
            float2 s1v = make_float2(0.f, 0.f);
#pragma unroll
            for (int jk = 0; jk < 9; ++jk)
                s1v = cfma(Dp[jk], B[jk], s1v);
            float2 a = alpha[(b * 32 + i) * 256 + t];
            acc = cfma(a, s1v, acc);
        }
        or1[bo * 256 + t] = acc;
    } else {
        int idx = bid - 256;
        int bo = idx & 255;
        int ic = idx >> 8;
        int b = bo >> 5, o = bo & 31;
        int wp = t >> 6, l = t & 63;
        {
            int i = ic * 4 + wp;
            float2 Ca[9];
#pragma unroll
            for (int jk = 0; jk < 9; ++jk) Ca[jk] = make_float2(0.f, 0.f);
#pragma unroll
            for (int k = 0; k < 4; ++k) {
                int e = l + 64 * k;
                int f = e >> 4, g = e & 15;
                float2 X[3], Xi[3];
                chi_basis(f, X);
                chi_basis(g, Xi);
                float2 a = alpha[(b * 32 + i) * 256 + e];
                float2 aX[3] = {cmul(a, X[0]), cmul(a, X[1]), cmul(a, X[2])};
#pragma unroll
                for (int j = 0; j < 3; ++j)
#pragma unroll
                    for (int k2 = 0; k2 < 3; ++k2)
                        Ca[j * 3 + k2] = cfma(aX[j], Xi[k2], Ca[j * 3 + k2]);
            }
#pragma unroll
            for (int jk = 0; jk < 9; ++jk) {
#pragma unroll
                for (int m = 32; m >= 1; m >>= 1) {
                    Ca[jk].x += __shfl_xor(Ca[jk].x, m);
                    Ca[jk].y += __shfl_xor(Ca[jk].y, m);
                }
            }
            if (l == 0) {
#pragma unroll
                for (int jk = 0; jk < 9; ++jk) CaL[wp][jk] = Ca[jk];
            }
        }
        __syncthreads();

        int p_ = t >> 4, q_ = t & 15;
        float2 acc = make_float2(0.f, 0.f);
#pragma unroll
        for (int ii = 0; ii < 4; ++ii) {
            int i = ic * 4 + ii;
            int io = i * 32 + o;
            float2 p1 = make_float2(wr[io * TOT + p_], wi[io * TOT + p_]);
            float i1 = 1.0f / (p1.x * p1.x + p1.y * p1.y);
            float2 phip = make_float2(-p1.x * i1, p1.y * i1);
            float2 p2 = make_float2(wr[io * TOT + 16 + q_], wi[io * TOT + 16 + q_]);
            float i2 = 1.0f / (p2.x * p2.x + p2.y * p2.y);
            float2 psip = make_float2(-p2.x * i2, p2.y * i2);
            float2 R = make_float2(wr[io * TOT + 32 + t], wi[io * TOT + 32 + t]);
            float2 c0 = CaL[ii][0], c1 = CaL[ii][1], c2 = CaL[ii][2];
            float2 c3 = CaL[ii][3], c4 = CaL[ii][4], c5 = CaL[ii][5];
            float2 c6 = CaL[ii][6], c7 = CaL[ii][7], c8 = CaL[ii][8];
            float2 col0 = cfma(c6, p1, cfma(c0, phip, c3));
            float2 col1 = cfma(c7, p1, cfma(c1, phip, c4));
            float2 col2 = cfma(c8, p1, cfma(c2, phip, c5));
            float2 T = cfma(col2, p2, cfma(col0, psip, col1));
            acc = cfma(R, T, acc);
        }
        or2p[(size_t)ic * 65536 + bo * 256 + t] = acc;
    }
}

// ============ k_x12m: single Fourier MFMA term + 4x4 Taylor polynomial for x2.
__global__ __launch_bounds__(512, 4) void k_x12m(
        const float2* __restrict__ or1v,
        const float2* __restrict__ or2p,
        const float2* __restrict__ Sv,
        const u16* __restrict__ fA,
        const u16* __restrict__ fB,
        float* __restrict__ out) {
    __shared__ u16 EA[2048];
    __shared__ u16 EB[4096];
    __shared__ u16 GL[2048];
    __shared__ float2 SM1[256];
    __shared__ float2 SM2[256];
    __shared__ float CP[16];

    const int t = threadIdx.x;
    const int l = t & 63, w = t >> 6;
    const int bid = blockIdx.x;
    const int o = bid & 31, b = (bid >> 5) & 7, zh = bid >> 8;
    const int bo = b * 32 + o;
    const int q = l & 15, c4 = l >> 4, k0 = c4 * 8;

    for (int ch = w; ch < 12; ch += 8) {
        const u16* g;
        u16* d;
        if (ch < 4) { g = fA + zh * 2048 + ch * 512 + l * 8; d = &EA[ch * 512]; }
        else { g = fB + (ch - 4) * 512 + l * 8; d = &EB[(ch - 4) * 512]; }
        __builtin_amdgcn_global_load_lds(
            (const __attribute__((address_space(1))) unsigned*)g,
            (__attribute__((address_space(3))) unsigned*)d, 16, 0, 0);
    }

    if (t < 256) {
        float sr = 0.f, si = 0.f;
#pragma unroll
        for (int ic = 0; ic < 8; ++ic) {
            float2 v = or2p[(size_t)ic * 65536 + bo * 256 + t];
            sr += v.x; si += v.y;
        }
        SM2[t] = make_float2(sr, si);
        SM1[t] = or1v[bo * 256 + t];
    }
    __syncthreads();

    {
        int gidx = t >> 5;
        int j = t & 31;
        const float2* Sg = Sv + (size_t)(o * 16 + gidx) * 256;
        float part = 0.f;
#pragma unroll
        for (int k = 0; k < 8; ++k) {
            int pq = j + 32 * k;
            float2 s = Sg[pq];
            float2 v = SM2[pq];
            part += v.x * s.x - v.y * s.y;
        }
#pragma unroll
        for (int msk = 16; msk >= 1; msk >>= 1)
            part += __shfl_xor(part, msk, 32);
        if (j == 0) CP[gidx] = part;
    }

    short8 mF0, mF1;
#pragma unroll
    for (int j = 0; j < 8; ++j) {
        int k = k0 + j, f = k & 15;
        float2 m1 = SM1[f * 16 + q];
        if (k < 16) { mF0[j] = (short)f2bf(m1.x); mF1[j] = (short)f2bf(m1.y); }
        else        { mF0[j] = (short)f2bf(-m1.y); mF1[j] = (short)f2bf(m1.x); }
    }
    const short8 bF = (w & 1) ? mF1 : mF0;

    const int zt_g = w >> 1;
    const int zL_g = zt_g * 16 + q;
    const int cw_g = c4 ^ ((zL_g >> 1) & 3);
    const int kk_g = q + ((w & 1) << 4);
    const int x_ = w * 16 + q;
    const int cb_ = c4 ^ ((x_ >> 1) & 3);

    {
        short8 aG = *(const short8*)&EA[zL_g * 32 + cw_g * 8];
        f32x4 g = (f32x4){0.f, 0.f, 0.f, 0.f};
        g = __builtin_amdgcn_mfma_f32_16x16x32_bf16(aG, bF, g, 0, 0, 0);
#pragma unroll
        for (int r = 0; r < 4; ++r) {
            int zz = zt_g * 16 + c4 * 4 + r;
            int cc = (kk_g >> 3) ^ ((zz >> 1) & 3);
            GL[zz * 32 + cc * 8 + (kk_g & 7)] = f2bf(g[r]);
        }
    }
    __syncthreads();

    f32x4 acc[4];
    {
        short8 bf = *(const short8*)&EB[x_ * 32 + cb_ * 8];
#pragma unroll
        for (int zt = 0; zt < 4; ++zt) {
            int zL = zt * 16 + q;
            int ca = c4 ^ ((zL >> 1) & 3);
            short8 af = *(const short8*)&GL[zL * 32 + ca * 8];
            f32x4 a = (f32x4){0.f, 0.f, 0.f, 0.f};
            acc[zt] = __builtin_amdgcn_mfma_f32_16x16x32_bf16(af, bf, a, 0, 0, 0);
        }
    }

    const float sc = 1.0f / 16384.0f;
    const float tx = (float)x_ * 0.007874015748031496f;
    float R[4];
#pragma unroll
    for (int n = 0; n < 4; ++n)
        R[n] = ((CP[n * 4 + 3] * tx + CP[n * 4 + 2]) * tx + CP[n * 4 + 1]) * tx + CP[n * 4 + 0];
#pragma unroll
    for (int zt = 0; zt < 4; ++zt) {
        int zbase = zh * 64 + zt * 16 + c4 * 4;
        f32x4 a = acc[zt];
#pragma unroll
        for (int r = 0; r < 4; ++r) {
            float tz = (float)(zbase + r) * 0.007874015748031496f;
            float poly = ((R[3] * tz + R[2]) * tz + R[1]) * tz + R[0];
            out[(size_t)bo * 16384 + (zbase + r) * 128 + x_] = a[r] * sc + poly;
        }
    }
}

extern "C" void kernel_launch(void* const* d_in, const int* in_sizes, int n_in,
                              void* d_out, int out_size, void* d_ws, size_t ws_size,
                              hipStream_t stream) {
    const float* x  = (const float*)d_in[0];
    const float* wr = (const float*)d_in[1];
    const float* wi = (const float*)d_in[2];
    float* out = (float*)d_out;
    float* ws = (float*)d_ws;

    float2* alpha = (float2*)(ws + 256);
    float2* T1    = (float2*)(ws + 131328);
    float2* Dv    = (float2*)(ws + 1179904);
    float2* or1   = (float2*)(ws + 1704192);
    float2* Sv    = (float2*)(ws + 1966336);
    u16*    fA    = (u16*)(ws + 6160640);
    u16*    fB    = (u16*)(ws + 6162688);
    float2* or2p  = (float2*)(ws + 6164736);

    hipLaunchKernelGGL(k_pre,    dim3(2209), dim3(256), 0, stream,
                       x, wr, wi, T1, Sv, Dv, fA, fB);
    hipLaunchKernelGGL(k_alpha2, dim3(256),  dim3(256), 0, stream, T1, alpha);
    hipLaunchKernelGGL(k_mid,    dim3(2304), dim3(256), 0, stream,
                       wr, wi, alpha, Dv, or1, or2p);
    hipLaunchKernelGGL(k_x12m,   dim3(512),  dim3(512), 0, stream,
                       or1, or2p, Sv, fA, fB, out);
}

// Round 9
// 55.222 us; speedup vs baseline: 1.2233x; 1.2233x over previous
//
#include <hip/hip_runtime.h>

#define TOT 288
#define W1C 6.2340979026f   // 2*pi*127/128
#define TWOPI_128 0.049087385212340517f

typedef short short8 __attribute__((ext_vector_type(8)));
typedef float f32x4 __attribute__((ext_vector_type(4)));
typedef unsigned short u16;
typedef u16 u16x8 __attribute__((ext_vector_type(8)));

__device__ __forceinline__ u16 f2bf(float f) {
    unsigned u = __builtin_bit_cast(unsigned, f);
    u += 0x7fffu + ((u >> 16) & 1u);
    return (u16)(u >> 16);
}
__device__ __forceinline__ float2 cmul(float2 a, float2 b) {
    return make_float2(a.x * b.x - a.y * b.y, a.x * b.y + a.y * b.x);
}
__device__ __forceinline__ float2 cfma(float2 a, float2 b, float2 c) {
    return make_float2(c.x + a.x * b.x - a.y * b.y, c.y + a.x * b.y + a.y * b.x);
}
__device__ __forceinline__ void chi_basis(int f, float2 c[3]) {
    if (f == 0) {
        c[0] = make_float2(1.f, 0.f); c[1] = make_float2(0.f, 0.f); c[2] = make_float2(0.f, 0.f);
    } else {
        float w = W1C * (float)f;
        float iw = 1.0f / w;
        c[0] = make_float2(0.f, 0.f);
        c[1] = make_float2(0.f, -iw);
        c[2] = make_float2(-iw * iw, 0.f);
    }
}

// ---------------- workspace layout (float offsets) ----------------
// alpha  :      256  (131072)   [b][i][f][g] float2
// T1     :   131328  (1048576)  [bi][f=16][x=128] float2
// Dv     :  1179904  (18432)    [o][i][jk=9] float2
// or1    :  1704192  (131072)   [b][o][f][g] float2
// S      :  1966336  (262144)   [o][nm=16][pq=256] float2
// fA     :  6160640  (2048)     bf16 Fourier A table
// fB     :  6162688  (2048)     bf16 Fourier B table
// or2p   :  6164736  (1048576)  partial or2 [ic=8][bo=256][pq=256] float2

// ============ k_pre: A1 Goertzel col-DFT (0..1023) | S (1024..1055) | D (1056..1183) | tf (1184)
__global__ __launch_bounds__(256) void k_pre(const float* __restrict__ x,
                                             const float* __restrict__ wr,
                                             const float* __restrict__ wi,
                                             float2* __restrict__ T1,
                                             float2* __restrict__ Sv,
                                             float2* __restrict__ Dv,
                                             u16* __restrict__ fA, u16* __restrict__ fB) {
    const int bid = blockIdx.x;
    const int t = threadIdx.x;

    if (bid < 1024) {
        // ----- A1: T1[bi,f,x] = sum_y X[bi,y,x] e^{-2pi i f y/128}, Goertzel -----
        // block = (bi, xchunk); thread: xc = chunk*32 + (t&31), f in {2*fg, 2*fg+1}, fg = t>>5.
        // Each image element is read by exactly ONE block (no cross-block redundancy).
        int bi = bid >> 2;
        int xc = ((bid & 3) << 5) + (t & 31);
        int f0 = (t >> 5) * 2;
        const float* xp = x + (size_t)bi * 16384 + xc;
        float wa = TWOPI_128 * (float)f0;
        float wb = TWOPI_128 * (float)(f0 + 1);
        float sa, ca, sb, cb;
        sincosf(wa, &sa, &ca);
        sincosf(wb, &sb, &cb);
        float c2a = 2.f * ca, c2b = 2.f * cb;
        float s1a = 0.f, s2a = 0.f, s1b = 0.f, s2b = 0.f;
#pragma unroll 4
        for (int y = 0; y < 128; ++y) {
            float xv = xp[(size_t)y * 128];
            float na = __builtin_fmaf(c2a, s1a, xv - s2a);
            s2a = s1a; s1a = na;
            float nb = __builtin_fmaf(c2b, s1b, xv - s2b);
            s2b = s1b; s1b = nb;
        }
        // X_f = e^{j w} s127 - s126  (real input)
        T1[(size_t)(bi * 16 + f0) * 128 + xc]     = make_float2(ca * s1a - s2a, sa * s1a);
        T1[(size_t)(bi * 16 + f0 + 1) * 128 + xc] = make_float2(cb * s1b - s2b, sb * s1b);
    } else if (bid < 1056) {
        // ----- S_o[n,m,p,q] Taylor moments for x2 polynomial -----
        int o = bid - 1024;
        int p = t >> 4, q = t & 15;
        float Sr[4][4], Si[4][4];
#pragma unroll
        for (int n = 0; n < 4; ++n)
#pragma unroll
            for (int m = 0; m < 4; ++m) { Sr[n][m] = 0.f; Si[n][m] = 0.f; }
        for (int i = 0; i < 32; ++i) {
            int io = i * 32 + o;
            float p1r = wr[io * TOT + p],      p1i = wi[io * TOT + p];
            float p2r = wr[io * TOT + 16 + q], p2i = wi[io * TOT + 16 + q];
            float a1r[4], a1i[4], a2r[4], a2i[4];
            a1r[0] = 1.f; a1i[0] = 0.f;
            a2r[0] = 1.f; a2i[0] = 0.f;
#pragma unroll
            for (int n = 1; n < 4; ++n) {
                a1r[n] = a1r[n-1] * p1r - a1i[n-1] * p1i;
                a1i[n] = a1r[n-1] * p1i + a1i[n-1] * p1r;
                a2r[n] = a2r[n-1] * p2r - a2i[n-1] * p2i;
                a2i[n] = a2r[n-1] * p2i + a2i[n-1] * p2r;
            }
#pragma unroll
            for (int n = 0; n < 4; ++n)
#pragma unroll
                for (int m = 0; m < 4; ++m) {
                    Sr[n][m] += a1r[n] * a2r[m] - a1i[n] * a2i[m];
                    Si[n][m] += a1r[n] * a2i[m] + a1i[n] * a2r[m];
                }
        }
        const float facs[4] = {1.f, 1.f, 0.5f, 0.16666666666f};
        const float isz = 1.0f / 16384.0f;
#pragma unroll
        for (int n = 0; n < 4; ++n)
#pragma unroll
            for (int m = 0; m < 4; ++m) {
                float fac = facs[n] * facs[m] * isz;
                Sv[(size_t)(o * 16 + n * 4 + m) * 256 + t] =
                    make_float2(Sr[n][m] * fac, Si[n][m] * fac);
            }
    } else if (bid < 1184) {
        // ----- D_jk[i,o] = sum_pq phi_j[p] * R[p,q] * psi_k[q] -----
        int base = (bid - 1056) * 8;
        int wp = t >> 6, l = t & 63;
#pragma unroll
        for (int s = 0; s < 2; ++s) {
            int io = base + wp * 2 + s;
            float2 Dacc[9];
#pragma unroll
            for (int jk = 0; jk < 9; ++jk) Dacc[jk] = make_float2(0.f, 0.f);
#pragma unroll
            for (int k = 0; k < 4; ++k) {
                int e = l + 64 * k;
                int p = e >> 4, q = e & 15;
                float2 p1 = make_float2(wr[io * TOT + p], wi[io * TOT + p]);
                float i1 = 1.0f / (p1.x * p1.x + p1.y * p1.y);
                float2 phip = make_float2(-p1.x * i1, p1.y * i1);
                float2 p2 = make_float2(wr[io * TOT + 16 + q], wi[io * TOT + 16 + q]);
                float i2 = 1.0f / (p2.x * p2.x + p2.y * p2.y);
                float2 psip = make_float2(-p2.x * i2, p2.y * i2);
                float2 R = make_float2(wr[io * TOT + 32 + e], wi[io * TOT + 32 + e]);
                float2 Rphi[3] = {cmul(R, phip), R, cmul(R, p1)};
                float2 psi[3] = {psip, make_float2(1.f, 0.f), p2};
#pragma unroll
                for (int j = 0; j < 3; ++j)
#pragma unroll
                    for (int k2 = 0; k2 < 3; ++k2)
                        Dacc[j * 3 + k2] = cfma(Rphi[j], psi[k2], Dacc[j * 3 + k2]);
            }
#pragma unroll
            for (int jk = 0; jk < 9; ++jk) {
#pragma unroll
                for (int m = 32; m >= 1; m >>= 1) {
                    Dacc[jk].x += __shfl_xor(Dacc[jk].x, m);
                    Dacc[jk].y += __shfl_xor(Dacc[jk].y, m);
                }
            }
            if (l == 0) {
                int o = io & 31, i = io >> 5;
#pragma unroll
                for (int jk = 0; jk < 9; ++jk)
                    Dv[(size_t)(o * 32 + i) * 9 + jk] = Dacc[jk];
            }
        }
    } else {
        // ----- tf: Fourier bf16 tables -----
        for (int cidx = t; cidx < 1024; cidx += 256) {
            int tbl = cidx >> 9, mc = cidx & 511;
            int z = mc >> 2, cp = mc & 3;
            int c = cp ^ ((z >> 1) & 3);
            u16x8 v;
#pragma unroll
            for (int j = 0; j < 8; ++j) {
                int k = c * 8 + j, f = k & 15, part = k >> 4;
                float th = TWOPI_128 * (float)((f * z) & 127);
                float s, cs;
                sincosf(th, &s, &cs);
                float val = part ? ((tbl == 0) ? s : -s) : cs;
                v[j] = f2bf(val);
            }
            u16* dst = (tbl == 0 ? fA : fB) + mc * 8;
            *(u16x8*)dst = v;
        }
    }
}

// ============ k_alpha2: row DFT via complex Goertzel.
// alpha[bi,f,g] = sum_x T1[bi,f,x] e^{-2pi i g x/128}
__global__ __launch_bounds__(256) void k_alpha2(const float2* __restrict__ T1,
                                                float2* __restrict__ alpha) {
    const int bi = blockIdx.x;
    const int t = threadIdx.x;
    const int f = t >> 4, g = t & 15;
    const float2* tp = T1 + (size_t)(bi * 16 + f) * 128;

    float w = TWOPI_128 * (float)g;
    float sw, cw;
    sincosf(w, &sw, &cw);
    float c2 = 2.f * cw;
    float s1r = 0.f, s1i = 0.f, s2r = 0.f, s2i = 0.f;
#pragma unroll 4
    for (int xx = 0; xx < 128; ++xx) {
        float2 v = tp[xx];
        float nr = __builtin_fmaf(c2, s1r, v.x - s2r);
        s2r = s1r; s1r = nr;
        float ni = __builtin_fmaf(c2, s1i, v.y - s2i);
        s2i = s1i; s1i = ni;
    }
    // alpha = e^{j w} s127 - s126  (complex input)
    alpha[bi * 256 + t] = make_float2(cw * s1r - sw * s1i - s2r,
                                      sw * s1r + cw * s1i - s2i);
}

// ============ k_mid: or1 (0..255) | or2p (256..2303)
__global__ __launch_bounds__(256) void k_mid(const float* __restrict__ wr,
                                             const float* __restrict__ wi,
                                             const float2* __restrict__ alpha,
                                             const float2* __restrict__ Dv,
                                             float2* __restrict__ or1,
                                             float2* __restrict__ or2p) {
    __shared__ float2 CaL[4][9];
    const int bid = blockIdx.x;
    const int t = threadIdx.x;

    if (bid < 256) {
        int bo = bid;
        int b = bo >> 5, o = bo & 31;
        int f = t >> 4, g = t & 15;
        float2 X[3], Xi[3];
        chi_basis(f, X);
        chi_basis(g, Xi);
        float2 B[9];
#pragma unroll
        for (int j = 0; j < 3; ++j)
#pragma unroll
            for (int k = 0; k < 3; ++k)
                B[j * 3 + k] = cmul(X[j], Xi[k]);
        float2 acc = make_float2(0.f, 0.f);
        for (int i = 0; i < 32; ++i) {
            const float2* Dp = Dv + (size_t)(o * 32 + i) * 9;
            float2 s1v = make_float2(0.f, 0.f);
#pragma unroll
            for (int jk = 0; jk < 9; ++jk)
                s1v = cfma(Dp[jk], B[jk], s1v);
            float2 a = alpha[(b * 32 + i) * 256 + t];
            acc = cfma(a, s1v, acc);
        }
        or1[bo * 256 + t] = acc;
    } else {
        int idx = bid - 256;
        int bo = idx & 255;
        int ic = idx >> 8;
        int b = bo >> 5, o = bo & 31;
        int wp = t >> 6, l = t & 63;
        {
            int i = ic * 4 + wp;
            float2 Ca[9];
#pragma unroll
            for (int jk = 0; jk < 9; ++jk) Ca[jk] = make_float2(0.f, 0.f);
#pragma unroll
            for (int k = 0; k < 4; ++k) {
                int e = l + 64 * k;
                int f = e >> 4, g = e & 15;
                float2 X[3], Xi[3];
                chi_basis(f, X);
                chi_basis(g, Xi);
                float2 a = alpha[(b * 32 + i) * 256 + e];
                float2 aX[3] = {cmul(a, X[0]), cmul(a, X[1]), cmul(a, X[2])};
#pragma unroll
                for (int j = 0; j < 3; ++j)
#pragma unroll
                    for (int k2 = 0; k2 < 3; ++k2)
                        Ca[j * 3 + k2] = cfma(aX[j], Xi[k2], Ca[j * 3 + k2]);
            }
#pragma unroll
            for (int jk = 0; jk < 9; ++jk) {
#pragma unroll
                for (int m = 32; m >= 1; m >>= 1) {
                    Ca[jk].x += __shfl_xor(Ca[jk].x, m);
                    Ca[jk].y += __shfl_xor(Ca[jk].y, m);
                }
            }
            if (l == 0) {
#pragma unroll
                for (int jk = 0; jk < 9; ++jk) CaL[wp][jk] = Ca[jk];
            }
        }
        __syncthreads();

        int p_ = t >> 4, q_ = t & 15;
        float2 acc = make_float2(0.f, 0.f);
#pragma unroll
        for (int ii = 0; ii < 4; ++ii) {
            int i = ic * 4 + ii;
            int io = i * 32 + o;
            float2 p1 = make_float2(wr[io * TOT + p_], wi[io * TOT + p_]);
            float i1 = 1.0f / (p1.x * p1.x + p1.y * p1.y);
            float2 phip = make_float2(-p1.x * i1, p1.y * i1);
            float2 p2 = make_float2(wr[io * TOT + 16 + q_], wi[io * TOT + 16 + q_]);
            float i2 = 1.0f / (p2.x * p2.x + p2.y * p2.y);
            float2 psip = make_float2(-p2.x * i2, p2.y * i2);
            float2 R = make_float2(wr[io * TOT + 32 + t], wi[io * TOT + 32 + t]);
            float2 c0 = CaL[ii][0], c1 = CaL[ii][1], c2 = CaL[ii][2];
            float2 c3 = CaL[ii][3], c4 = CaL[ii][4], c5 = CaL[ii][5];
            float2 c6 = CaL[ii][6], c7 = CaL[ii][7], c8 = CaL[ii][8];
            float2 col0 = cfma(c6, p1, cfma(c0, phip, c3));
            float2 col1 = cfma(c7, p1, cfma(c1, phip, c4));
            float2 col2 = cfma(c8, p1, cfma(c2, phip, c5));
            float2 T = cfma(col2, p2, cfma(col0, psip, col1));
            acc = cfma(R, T, acc);
        }
        or2p[(size_t)ic * 65536 + bo * 256 + t] = acc;
    }
}

// ============ k_x12m: single Fourier MFMA term + 4x4 Taylor polynomial for x2.
__global__ __launch_bounds__(512, 4) void k_x12m(
        const float2* __restrict__ or1v,
        const float2* __restrict__ or2p,
        const float2* __restrict__ Sv,
        const u16* __restrict__ fA,
        const u16* __restrict__ fB,
        float* __restrict__ out) {
    __shared__ u16 EA[2048];
    __shared__ u16 EB[4096];
    __shared__ u16 GL[2048];
    __shared__ float2 SM1[256];
    __shared__ float2 SM2[256];
    __shared__ float CP[16];

    const int t = threadIdx.x;
    const int l = t & 63, w = t >> 6;
    const int bid = blockIdx.x;
    const int o = bid & 31, b = (bid >> 5) & 7, zh = bid >> 8;
    const int bo = b * 32 + o;
    const int q = l & 15, c4 = l >> 4, k0 = c4 * 8;

    for (int ch = w; ch < 12; ch += 8) {
        const u16* g;
        u16* d;
        if (ch < 4) { g = fA + zh * 2048 + ch * 512 + l * 8; d = &EA[ch * 512]; }
        else { g = fB + (ch - 4) * 512 + l * 8; d = &EB[(ch - 4) * 512]; }
        __builtin_amdgcn_global_load_lds(
            (const __attribute__((address_space(1))) unsigned*)g,
            (__attribute__((address_space(3))) unsigned*)d, 16, 0, 0);
    }

    if (t < 256) {
        float sr = 0.f, si = 0.f;
#pragma unroll
        for (int ic = 0; ic < 8; ++ic) {
            float2 v = or2p[(size_t)ic * 65536 + bo * 256 + t];
            sr += v.x; si += v.y;
        }
        SM2[t] = make_float2(sr, si);
        SM1[t] = or1v[bo * 256 + t];
    }
    __syncthreads();

    {
        int gidx = t >> 5;
        int j = t & 31;
        const float2* Sg = Sv + (size_t)(o * 16 + gidx) * 256;
        float part = 0.f;
#pragma unroll
        for (int k = 0; k < 8; ++k) {
            int pq = j + 32 * k;
            float2 s = Sg[pq];
            float2 v = SM2[pq];
            part += v.x * s.x - v.y * s.y;
        }
#pragma unroll
        for (int msk = 16; msk >= 1; msk >>= 1)
            part += __shfl_xor(part, msk, 32);
        if (j == 0) CP[gidx] = part;
    }

    short8 mF0, mF1;
#pragma unroll
    for (int j = 0; j < 8; ++j) {
        int k = k0 + j, f = k & 15;
        float2 m1 = SM1[f * 16 + q];
        if (k < 16) { mF0[j] = (short)f2bf(m1.x); mF1[j] = (short)f2bf(m1.y); }
        else        { mF0[j] = (short)f2bf(-m1.y); mF1[j] = (short)f2bf(m1.x); }
    }
    const short8 bF = (w & 1) ? mF1 : mF0;

    const int zt_g = w >> 1;
    const int zL_g = zt_g * 16 + q;
    const int cw_g = c4 ^ ((zL_g >> 1) & 3);
    const int kk_g = q + ((w & 1) << 4);
    const int x_ = w * 16 + q;
    const int cb_ = c4 ^ ((x_ >> 1) & 3);

    {
        short8 aG = *(const short8*)&EA[zL_g * 32 + cw_g * 8];
        f32x4 g = (f32x4){0.f, 0.f, 0.f, 0.f};
        g = __builtin_amdgcn_mfma_f32_16x16x32_bf16(aG, bF, g, 0, 0, 0);
#pragma unroll
        for (int r = 0; r < 4; ++r) {
            int zz = zt_g * 16 + c4 * 4 + r;
            int cc = (kk_g >> 3) ^ ((zz >> 1) & 3);
            GL[zz * 32 + cc * 8 + (kk_g & 7)] = f2bf(g[r]);
        }
    }
    __syncthreads();

    f32x4 acc[4];
    {
        short8 bf = *(const short8*)&EB[x_ * 32 + cb_ * 8];
#pragma unroll
        for (int zt = 0; zt < 4; ++zt) {
            int zL = zt * 16 + q;
            int ca = c4 ^ ((zL >> 1) & 3);
            short8 af = *(const short8*)&GL[zL * 32 + ca * 8];
            f32x4 a = (f32x4){0.f, 0.f, 0.f, 0.f};
            acc[zt] = __builtin_amdgcn_mfma_f32_16x16x32_bf16(af, bf, a, 0, 0, 0);
        }
    }

    const float sc = 1.0f / 16384.0f;
    const float tx = (float)x_ * 0.007874015748031496f;
    float R[4];
#pragma unroll
    for (int n = 0; n < 4; ++n)
        R[n] = ((CP[n * 4 + 3] * tx + CP[n * 4 + 2]) * tx + CP[n * 4 + 1]) * tx + CP[n * 4 + 0];
#pragma unroll
    for (int zt = 0; zt < 4; ++zt) {
        int zbase = zh * 64 + zt * 16 + c4 * 4;
        f32x4 a = acc[zt];
#pragma unroll
        for (int r = 0; r < 4; ++r) {
            float tz = (float)(zbase + r) * 0.007874015748031496f;
            float poly = ((R[3] * tz + R[2]) * tz + R[1]) * tz + R[0];
            out[(size_t)bo * 16384 + (zbase + r) * 128 + x_] = a[r] * sc + poly;
        }
    }
}

extern "C" void kernel_launch(void* const* d_in, const int* in_sizes, int n_in,
                              void* d_out, int out_size, void* d_ws, size_t ws_size,
                              hipStream_t stream) {
    const float* x  = (const float*)d_in[0];
    const float* wr = (const float*)d_in[1];
    const float* wi = (const float*)d_in[2];
    float* out = (float*)d_out;
    float* ws = (float*)d_ws;

    float2* alpha = (float2*)(ws + 256);
    float2* T1    = (float2*)(ws + 131328);
    float2* Dv    = (float2*)(ws + 1179904);
    float2* or1   = (float2*)(ws + 1704192);
    float2* Sv    = (float2*)(ws + 1966336);
    u16*    fA    = (u16*)(ws + 6160640);
    u16*    fB    = (u16*)(ws + 6162688);
    float2* or2p  = (float2*)(ws + 6164736);

    hipLaunchKernelGGL(k_pre,    dim3(1185), dim3(256), 0, stream,
                       x, wr, wi, T1, Sv, Dv, fA, fB);
    hipLaunchKernelGGL(k_alpha2, dim3(256),  dim3(256), 0, stream, T1, alpha);
    hipLaunchKernelGGL(k_mid,    dim3(2304), dim3(256), 0, stream,
                       wr, wi, alpha, Dv, or1, or2p);
    hipLaunchKernelGGL(k_x12m,   dim3(512),  dim3(512), 0, stream,
                       or1, or2p, Sv, fA, fB, out);
}

// Round 10
// 54.360 us; speedup vs baseline: 1.2427x; 1.0159x over previous
//
#include <hip/hip_runtime.h>

#define TOT 288
#define W1C 6.2340979026f   // 2*pi*127/128
#define TWOPI_128 0.049087385212340517f

typedef short short8 __attribute__((ext_vector_type(8)));
typedef float f32x4 __attribute__((ext_vector_type(4)));
typedef unsigned short u16;
typedef u16 u16x8 __attribute__((ext_vector_type(8)));

__device__ __forceinline__ u16 f2bf(float f) {
    unsigned u = __builtin_bit_cast(unsigned, f);
    u += 0x7fffu + ((u >> 16) & 1u);
    return (u16)(u >> 16);
}
__device__ __forceinline__ float2 cmul(float2 a, float2 b) {
    return make_float2(a.x * b.x - a.y * b.y, a.x * b.y + a.y * b.x);
}
__device__ __forceinline__ float2 cfma(float2 a, float2 b, float2 c) {
    return make_float2(c.x + a.x * b.x - a.y * b.y, c.y + a.x * b.y + a.y * b.x);
}
__device__ __forceinline__ void chi_basis(int f, float2 c[3]) {
    if (f == 0) {
        c[0] = make_float2(1.f, 0.f); c[1] = make_float2(0.f, 0.f); c[2] = make_float2(0.f, 0.f);
    } else {
        float w = W1C * (float)f;
        float iw = 1.0f / w;
        c[0] = make_float2(0.f, 0.f);
        c[1] = make_float2(0.f, -iw);
        c[2] = make_float2(-iw * iw, 0.f);
    }
}

// ---------------- workspace layout (float offsets) ----------------
// alpha  :      256  (131072)   [b][i][f][g] float2
// Dv     :  1179904  (18432)    [o][i][jk=9] float2
// or1    :  1704192  (131072)   [b][o][f][g] float2
// S      :  1966336  (262144)   [o][nm=16][pq=256] float2
// fA     :  6160640  (2048)     bf16 Fourier A table
// fB     :  6162688  (2048)     bf16 Fourier B table
// or2p   :  6164736  (1048576)  partial or2 [ic=8][bo=256][pq=256] float2

// ============ k_pre: alpha fused 2D-Goertzel (0..255) | S (256..287) | D (288..415) | tf (416)
__global__ __launch_bounds__(256) void k_pre(const float* __restrict__ x,
                                             const float* __restrict__ wr,
                                             const float* __restrict__ wi,
                                             float2* __restrict__ alpha,
                                             float2* __restrict__ Sv,
                                             float2* __restrict__ Dv,
                                             u16* __restrict__ fA, u16* __restrict__ fB) {
    __shared__ float sm[4352];          // alpha branch: float2 T1c[16][132] = 16896 B
    const int bid = blockIdx.x;
    const int t = threadIdx.x;

    if (bid < 256) {
        // ----- alpha[bi,f,g]: 16x16 corner of 2D DFT, both passes Goertzel, LDS intermediate -----
        float2* T1c = (float2*)sm;      // [16][132] padded
        const int bi = bid;
        const float* xp = x + (size_t)bi * 16384;
        const int xc = t & 127;
        const int ft = (t >> 7) * 8;    // this thread's 8 f's: ft..ft+7

        // phase 1: column DFT. T1[f,xc] = sum_y x[y,xc] e^{-2pi i f y/128}
        float c2[8], ccs[8], csn[8], s1[8], s2[8];
#pragma unroll
        for (int j = 0; j < 8; ++j) {
            float w = TWOPI_128 * (float)(ft + j);
            sincosf(w, &csn[j], &ccs[j]);
            c2[j] = 2.f * ccs[j];
            s1[j] = 0.f; s2[j] = 0.f;
        }
#pragma unroll 2
        for (int y = 0; y < 128; ++y) {
            float xv = xp[(size_t)y * 128 + xc];
#pragma unroll
            for (int j = 0; j < 8; ++j) {
                float na = __builtin_fmaf(c2[j], s1[j], xv - s2[j]);
                s2[j] = s1[j]; s1[j] = na;
            }
        }
#pragma unroll
        for (int j = 0; j < 8; ++j)
            T1c[(ft + j) * 132 + xc] = make_float2(ccs[j] * s1[j] - s2[j], csn[j] * s1[j]);
        __syncthreads();

        // phase 2: row DFT over complex T1 (broadcast LDS reads, conflict-free)
        const int f = t >> 4, g = t & 15;
        const float2* tp = T1c + f * 132;
        float sw, cw;
        sincosf(TWOPI_128 * (float)g, &sw, &cw);
        float c2g = 2.f * cw;
        float s1r = 0.f, s1i = 0.f, s2r = 0.f, s2i = 0.f;
#pragma unroll 4
        for (int xx = 0; xx < 128; ++xx) {
            float2 v = tp[xx];
            float nr = __builtin_fmaf(c2g, s1r, v.x - s2r);
            s2r = s1r; s1r = nr;
            float ni = __builtin_fmaf(c2g, s1i, v.y - s2i);
            s2i = s1i; s1i = ni;
        }
        alpha[bi * 256 + t] = make_float2(cw * s1r - sw * s1i - s2r,
                                          sw * s1r + cw * s1i - s2i);
    } else if (bid < 288) {
        // ----- S_o[n,m,p,q] Taylor moments for x2 polynomial -----
        int o = bid - 256;
        int p = t >> 4, q = t & 15;
        float Sr[4][4], Si[4][4];
#pragma unroll
        for (int n = 0; n < 4; ++n)
#pragma unroll
            for (int m = 0; m < 4; ++m) { Sr[n][m] = 0.f; Si[n][m] = 0.f; }
        for (int i = 0; i < 32; ++i) {
            int io = i * 32 + o;
            float p1r = wr[io * TOT + p],      p1i = wi[io * TOT + p];
            float p2r = wr[io * TOT + 16 + q], p2i = wi[io * TOT + 16 + q];
            float a1r[4], a1i[4], a2r[4], a2i[4];
            a1r[0] = 1.f; a1i[0] = 0.f;
            a2r[0] = 1.f; a2i[0] = 0.f;
#pragma unroll
            for (int n = 1; n < 4; ++n) {
                a1r[n] = a1r[n-1] * p1r - a1i[n-1] * p1i;
                a1i[n] = a1r[n-1] * p1i + a1i[n-1] * p1r;
                a2r[n] = a2r[n-1] * p2r - a2i[n-1] * p2i;
                a2i[n] = a2r[n-1] * p2i + a2i[n-1] * p2r;
            }
#pragma unroll
            for (int n = 0; n < 4; ++n)
#pragma unroll
                for (int m = 0; m < 4; ++m) {
                    Sr[n][m] += a1r[n] * a2r[m] - a1i[n] * a2i[m];
                    Si[n][m] += a1r[n] * a2i[m] + a1i[n] * a2r[m];
                }
        }
        const float facs[4] = {1.f, 1.f, 0.5f, 0.16666666666f};
        const float isz = 1.0f / 16384.0f;
#pragma unroll
        for (int n = 0; n < 4; ++n)
#pragma unroll
            for (int m = 0; m < 4; ++m) {
                float fac = facs[n] * facs[m] * isz;
                Sv[(size_t)(o * 16 + n * 4 + m) * 256 + t] =
                    make_float2(Sr[n][m] * fac, Si[n][m] * fac);
            }
    } else if (bid < 416) {
        // ----- D_jk[i,o] = sum_pq phi_j[p] * R[p,q] * psi_k[q] -----
        int base = (bid - 288) * 8;
        int wp = t >> 6, l = t & 63;
#pragma unroll
        for (int s = 0; s < 2; ++s) {
            int io = base + wp * 2 + s;
            float2 Dacc[9];
#pragma unroll
            for (int jk = 0; jk < 9; ++jk) Dacc[jk] = make_float2(0.f, 0.f);
#pragma unroll
            for (int k = 0; k < 4; ++k) {
                int e = l + 64 * k;
                int p = e >> 4, q = e & 15;
                float2 p1 = make_float2(wr[io * TOT + p], wi[io * TOT + p]);
                float i1 = 1.0f / (p1.x * p1.x + p1.y * p1.y);
                float2 phip = make_float2(-p1.x * i1, p1.y * i1);
                float2 p2 = make_float2(wr[io * TOT + 16 + q], wi[io * TOT + 16 + q]);
                float i2 = 1.0f / (p2.x * p2.x + p2.y * p2.y);
                float2 psip = make_float2(-p2.x * i2, p2.y * i2);
                float2 R = make_float2(wr[io * TOT + 32 + e], wi[io * TOT + 32 + e]);
                float2 Rphi[3] = {cmul(R, phip), R, cmul(R, p1)};
                float2 psi[3] = {psip, make_float2(1.f, 0.f), p2};
#pragma unroll
                for (int j = 0; j < 3; ++j)
#pragma unroll
                    for (int k2 = 0; k2 < 3; ++k2)
                        Dacc[j * 3 + k2] = cfma(Rphi[j], psi[k2], Dacc[j * 3 + k2]);
            }
#pragma unroll
            for (int jk = 0; jk < 9; ++jk) {
#pragma unroll
                for (int m = 32; m >= 1; m >>= 1) {
                    Dacc[jk].x += __shfl_xor(Dacc[jk].x, m);
                    Dacc[jk].y += __shfl_xor(Dacc[jk].y, m);
                }
            }
            if (l == 0) {
                int o = io & 31, i = io >> 5;
#pragma unroll
                for (int jk = 0; jk < 9; ++jk)
                    Dv[(size_t)(o * 32 + i) * 9 + jk] = Dacc[jk];
            }
        }
    } else {
        // ----- tf: Fourier bf16 tables -----
        for (int cidx = t; cidx < 1024; cidx += 256) {
            int tbl = cidx >> 9, mc = cidx & 511;
            int z = mc >> 2, cp = mc & 3;
            int c = cp ^ ((z >> 1) & 3);
            u16x8 v;
#pragma unroll
            for (int j = 0; j < 8; ++j) {
                int k = c * 8 + j, f = k & 15, part = k >> 4;
                float th = TWOPI_128 * (float)((f * z) & 127);
                float s, cs;
                sincosf(th, &s, &cs);
                float val = part ? ((tbl == 0) ? s : -s) : cs;
                v[j] = f2bf(val);
            }
            u16* dst = (tbl == 0 ? fA : fB) + mc * 8;
            *(u16x8*)dst = v;
        }
    }
}

// ============ k_mid: or1 (0..255) | or2p (256..2303)
__global__ __launch_bounds__(256) void k_mid(const float* __restrict__ wr,
                                             const float* __restrict__ wi,
                                             const float2* __restrict__ alpha,
                                             const float2* __restrict__ Dv,
                                             float2* __restrict__ or1,
                                             float2* __restrict__ or2p) {
    __shared__ float2 CaL[4][9];
    const int bid = blockIdx.x;
    const int t = threadIdx.x;

    if (bid < 256) {
        int bo = bid;
        int b = bo >> 5, o = bo & 31;
        int f = t >> 4, g = t & 15;
        float2 X[3], Xi[3];
        chi_basis(f, X);
        chi_basis(g, Xi);
        float2 B[9];
#pragma unroll
        for (int j = 0; j < 3; ++j)
#pragma unroll
            for (int k = 0; k < 3; ++k)
                B[j * 3 + k] = cmul(X[j], Xi[k]);
        float2 acc = make_float2(0.f, 0.f);
        for (int i = 0; i < 32; ++i) {
            const float2* Dp = Dv + (size_t)(o * 32 + i) * 9;
            float2 s1v = make_float2(0.f, 0.f);
#pragma unroll
            for (int jk = 0; jk < 9; ++jk)
                s1v = cfma(Dp[jk], B[jk], s1v);
            float2 a = alpha[(b * 32 + i) * 256 + t];
            acc = cfma(a, s1v, acc);
        }
        or1[bo * 256 + t] = acc;
    } else {
        int idx = bid - 256;
        int bo = idx & 255;
        int ic = idx >> 8;
        int b = bo >> 5, o = bo & 31;
        int wp = t >> 6, l = t & 63;
        {
            int i = ic * 4 + wp;
            float2 Ca[9];
#pragma unroll
            for (int jk = 0; jk < 9; ++jk) Ca[jk] = make_float2(0.f, 0.f);
#pragma unroll
            for (int k = 0; k < 4; ++k) {
                int e = l + 64 * k;
                int f = e >> 4, g = e & 15;
                float2 X[3], Xi[3];
                chi_basis(f, X);
                chi_basis(g, Xi);
                float2 a = alpha[(b * 32 + i) * 256 + e];
                float2 aX[3] = {cmul(a, X[0]), cmul(a, X[1]), cmul(a, X[2])};
#pragma unroll
                for (int j = 0; j < 3; ++j)
#pragma unroll
                    for (int k2 = 0; k2 < 3; ++k2)
                        Ca[j * 3 + k2] = cfma(aX[j], Xi[k2], Ca[j * 3 + k2]);
            }
#pragma unroll
            for (int jk = 0; jk < 9; ++jk) {
#pragma unroll
                for (int m = 32; m >= 1; m >>= 1) {
                    Ca[jk].x += __shfl_xor(Ca[jk].x, m);
                    Ca[jk].y += __shfl_xor(Ca[jk].y, m);
                }
            }
            if (l == 0) {
#pragma unroll
                for (int jk = 0; jk < 9; ++jk) CaL[wp][jk] = Ca[jk];
            }
        }
        __syncthreads();

        int p_ = t >> 4, q_ = t & 15;
        float2 acc = make_float2(0.f, 0.f);
#pragma unroll
        for (int ii = 0; ii < 4; ++ii) {
            int i = ic * 4 + ii;
            int io = i * 32 + o;
            float2 p1 = make_float2(wr[io * TOT + p_], wi[io * TOT + p_]);
            float i1 = 1.0f / (p1.x * p1.x + p1.y * p1.y);
            float2 phip = make_float2(-p1.x * i1, p1.y * i1);
            float2 p2 = make_float2(wr[io * TOT + 16 + q_], wi[io * TOT + 16 + q_]);
            float i2 = 1.0f / (p2.x * p2.x + p2.y * p2.y);
            float2 psip = make_float2(-p2.x * i2, p2.y * i2);
            float2 R = make_float2(wr[io * TOT + 32 + t], wi[io * TOT + 32 + t]);
            float2 c0 = CaL[ii][0], c1 = CaL[ii][1], c2 = CaL[ii][2];
            float2 c3 = CaL[ii][3], c4 = CaL[ii][4], c5 = CaL[ii][5];
            float2 c6 = CaL[ii][6], c7 = CaL[ii][7], c8 = CaL[ii][8];
            float2 col0 = cfma(c6, p1, cfma(c0, phip, c3));
            float2 col1 = cfma(c7, p1, cfma(c1, phip, c4));
            float2 col2 = cfma(c8, p1, cfma(c2, phip, c5));
            float2 T = cfma(col2, p2, cfma(col0, psip, col1));
            acc = cfma(R, T, acc);
        }
        or2p[(size_t)ic * 65536 + bo * 256 + t] = acc;
    }
}

// ============ k_x12m: single Fourier MFMA term + 4x4 Taylor polynomial for x2.
__global__ __launch_bounds__(512, 4) void k_x12m(
        const float2* __restrict__ or1v,
        const float2* __restrict__ or2p,
        const float2* __restrict__ Sv,
        const u16* __restrict__ fA,
        const u16* __restrict__ fB,
        float* __restrict__ out) {
    __shared__ u16 EA[2048];
    __shared__ u16 EB[4096];
    __shared__ u16 GL[2048];
    __shared__ float2 SM1[256];
    __shared__ float2 SM2[256];
    __shared__ float CP[16];

    const int t = threadIdx.x;
    const int l = t & 63, w = t >> 6;
    const int bid = blockIdx.x;
    const int o = bid & 31, b = (bid >> 5) & 7, zh = bid >> 8;
    const int bo = b * 32 + o;
    const int q = l & 15, c4 = l >> 4, k0 = c4 * 8;

    for (int ch = w; ch < 12; ch += 8) {
        const u16* g;
        u16* d;
        if (ch < 4) { g = fA + zh * 2048 + ch * 512 + l * 8; d = &EA[ch * 512]; }
        else { g = fB + (ch - 4) * 512 + l * 8; d = &EB[(ch - 4) * 512]; }
        __builtin_amdgcn_global_load_lds(
            (const __attribute__((address_space(1))) unsigned*)g,
            (__attribute__((address_space(3))) unsigned*)d, 16, 0, 0);
    }

    if (t < 256) {
        float sr = 0.f, si = 0.f;
#pragma unroll
        for (int ic = 0; ic < 8; ++ic) {
            float2 v = or2p[(size_t)ic * 65536 + bo * 256 + t];
            sr += v.x; si += v.y;
        }
        SM2[t] = make_float2(sr, si);
        SM1[t] = or1v[bo * 256 + t];
    }
    __syncthreads();

    {
        int gidx = t >> 5;
        int j = t & 31;
        const float2* Sg = Sv + (size_t)(o * 16 + gidx) * 256;
        float part = 0.f;
#pragma unroll
        for (int k = 0; k < 8; ++k) {
            int pq = j + 32 * k;
            float2 s = Sg[pq];
            float2 v = SM2[pq];
            part += v.x * s.x - v.y * s.y;
        }
#pragma unroll
        for (int msk = 16; msk >= 1; msk >>= 1)
            part += __shfl_xor(part, msk, 32);
        if (j == 0) CP[gidx] = part;
    }

    short8 mF0, mF1;
#pragma unroll
    for (int j = 0; j < 8; ++j) {
        int k = k0 + j, f = k & 15;
        float2 m1 = SM1[f * 16 + q];
        if (k < 16) { mF0[j] = (short)f2bf(m1.x); mF1[j] = (short)f2bf(m1.y); }
        else        { mF0[j] = (short)f2bf(-m1.y); mF1[j] = (short)f2bf(m1.x); }
    }
    const short8 bF = (w & 1) ? mF1 : mF0;

    const int zt_g = w >> 1;
    const int zL_g = zt_g * 16 + q;
    const int cw_g = c4 ^ ((zL_g >> 1) & 3);
    const int kk_g = q + ((w & 1) << 4);
    const int x_ = w * 16 + q;
    const int cb_ = c4 ^ ((x_ >> 1) & 3);

    {
        short8 aG = *(const short8*)&EA[zL_g * 32 + cw_g * 8];
        f32x4 g = (f32x4){0.f, 0.f, 0.f, 0.f};
        g = __builtin_amdgcn_mfma_f32_16x16x32_bf16(aG, bF, g, 0, 0, 0);
#pragma unroll
        for (int r = 0; r < 4; ++r) {
            int zz = zt_g * 16 + c4 * 4 + r;
            int cc = (kk_g >> 3) ^ ((zz >> 1) & 3);
            GL[zz * 32 + cc * 8 + (kk_g & 7)] = f2bf(g[r]);
        }
    }
    __syncthreads();

    f32x4 acc[4];
    {
        short8 bf = *(const short8*)&EB[x_ * 32 + cb_ * 8];
#pragma unroll
        for (int zt = 0; zt < 4; ++zt) {
            int zL = zt * 16 + q;
            int ca = c4 ^ ((zL >> 1) & 3);
            short8 af = *(const short8*)&GL[zL * 32 + ca * 8];
            f32x4 a = (f32x4){0.f, 0.f, 0.f, 0.f};
            acc[zt] = __builtin_amdgcn_mfma_f32_16x16x32_bf16(af, bf, a, 0, 0, 0);
        }
    }

    const float sc = 1.0f / 16384.0f;
    const float tx = (float)x_ * 0.007874015748031496f;
    float R[4];
#pragma unroll
    for (int n = 0; n < 4; ++n)
        R[n] = ((CP[n * 4 + 3] * tx + CP[n * 4 + 2]) * tx + CP[n * 4 + 1]) * tx + CP[n * 4 + 0];
#pragma unroll
    for (int zt = 0; zt < 4; ++zt) {
        int zbase = zh * 64 + zt * 16 + c4 * 4;
        f32x4 a = acc[zt];
#pragma unroll
        for (int r = 0; r < 4; ++r) {
            float tz = (float)(zbase + r) * 0.007874015748031496f;
            float poly = ((R[3] * tz + R[2]) * tz + R[1]) * tz + R[0];
            out[(size_t)bo * 16384 + (zbase + r) * 128 + x_] = a[r] * sc + poly;
        }
    }
}

extern "C" void kernel_launch(void* const* d_in, const int* in_sizes, int n_in,
                              void* d_out, int out_size, void* d_ws, size_t ws_size,
                              hipStream_t stream) {
    const float* x  = (const float*)d_in[0];
    const float* wr = (const float*)d_in[1];
    const float* wi = (const float*)d_in[2];
    float* out = (float*)d_out;
    float* ws = (float*)d_ws;

    float2* alpha = (float2*)(ws + 256);
    float2* Dv    = (float2*)(ws + 1179904);
    float2* or1   = (float2*)(ws + 1704192);
    float2* Sv    = (float2*)(ws + 1966336);
    u16*    fA    = (u16*)(ws + 6160640);
    u16*    fB    = (u16*)(ws + 6162688);
    float2* or2p  = (float2*)(ws + 6164736);

    hipLaunchKernelGGL(k_pre,  dim3(417),  dim3(256), 0, stream,
                       x, wr, wi, alpha, Sv, Dv, fA, fB);
    hipLaunchKernelGGL(k_mid,  dim3(2304), dim3(256), 0, stream,
                       wr, wi, alpha, Dv, or1, or2p);
    hipLaunchKernelGGL(k_x12m, dim3(512),  dim3(512), 0, stream,
                       or1, or2p, Sv, fA, fB, out);
}